// Round 10
// baseline (6243.270 us; speedup 1.0000x reference)
//
#include <hip/hip_runtime.h>
#include <hip/hip_fp16.h>
#include <cmath>

// Problem constants (reference: B=256, T=512, IN=64, R=2048)
constexpr int kB  = 256;
constexpr int kT  = 512;
constexpr int kIN = 64;
constexpr int kR  = 2048;

constexpr int kBands  = 8;             // m-bands; band = blockIdx&7 -> XCD-local under
                                       // round-robin dispatch (perf heuristic only)
constexpr int kNB     = 64;            // n-blocks per band
constexpr int kBlocks = kBands * kNB;  // 512 blocks -> 2 blocks/CU (latency hiding)
constexpr int BM = 32;                 // batches per block
constexpr int BN = 32;                 // n per block (W-band in registers)
constexpr int CH  = 256;               // k per staged s-chunk (= 8 producer blocks)
constexpr int NCH = kR / CH;           // 8 chunks = 8 flag groups
constexpr int SST = CH + 8;            // ss row stride (halfs) = 264 (min-cycle banks)
constexpr int PFS = 36;                // partial-scratch row stride (words)

typedef _Float16 f16x8 __attribute__((ext_vector_type(8)));
typedef float    f32x4 __attribute__((ext_vector_type(4)));
typedef unsigned long long u64;

#define MFMA16(a, b, c) __builtin_amdgcn_mfma_f32_16x16x32_f16((a), (b), (c), 0, 0, 0)

__device__ __forceinline__ f16x8 cvt8(float4 a, float4 b) {
    f16x8 v;
    v[0] = (_Float16)a.x; v[1] = (_Float16)a.y; v[2] = (_Float16)a.z; v[3] = (_Float16)a.w;
    v[4] = (_Float16)b.x; v[5] = (_Float16)b.y; v[6] = (_Float16)b.z; v[7] = (_Float16)b.w;
    return v;
}

// One coalesced poll of the band's 64 per-block flags (agent-scope, L3-fresh).
// Bit j of the returned mask: band-block j has published step >= target.
__device__ __forceinline__ u64 poll_flags(const unsigned* f, int lane, unsigned target) {
    unsigned v = __hip_atomic_load(f + lane, __ATOMIC_RELAXED, __HIP_MEMORY_SCOPE_AGENT);
    return __ballot(v >= target);
}
// Chunk pc (256 k) is produced by band-blocks [8*pc, 8*pc+8).
__device__ __forceinline__ bool chunk_ready(u64 fm, int pc) {
    return ((fm >> (8 * pc)) & 0xffull) == 0xffull;
}

// Persistent ESN, r10: 2 blocks/CU for TLP latency hiding (the r9 post-mortem
// showed ~40% of step time is pure waiting with 1 block/CU).
// 8 bands (band = blockIdx&7, closed producer/consumer systems, XCD-co-located
// under round-robin dispatch) x 64 n-blocks. Block = 256 threads = 4 waves =
// 4 k-phases q; BM=32, BN=32 (2 m-tiles x 2 n-tiles per wave). K-loop: NCH=8
// ring-ordered chunks (CH=256, ring start = own producer group) over
// double-buffered LDS with depth-2 register prefetch.
// Coherence (r5-proven, unchanged): agent-scope write-through s-stores ->
// s_waitcnt drain -> __syncthreads -> flag store; consumers: ONE acquire-inv
// per block per step, then plain cached coalesced loads. Skew within a band
// is < 2 steps (every block consumes all 8 chunks each step), so ping-pong
// buffer reuse is safe.
__global__ __launch_bounds__(256, 2) void esn_persist(
    const float* __restrict__ X,     // [B, T, IN]
    const float* __restrict__ Win,   // [R, IN]
    const float* __restrict__ W,     // [R, R]
    float* __restrict__ out,         // [B, R]
    _Float16* __restrict__ sbuf0,
    _Float16* __restrict__ sbuf1,
    unsigned* __restrict__ flags)    // [8][64], zeroed at launch
{
    __shared__ __align__(16) _Float16 ss[2][BM * SST];   // 33792 B
    __shared__ __align__(16) float pf[4 * BM * PFS];     // 18432 B
    __shared__ u64 fm_sh;

    const int tid  = threadIdx.x;
    const int wave = tid >> 6, lane = tid & 63;
    const int quad = lane >> 4, l16 = lane & 15;
    const int q  = wave;             // k-phase: window ≡ q (mod 4)
    const int mb = blockIdx.x & 7;   // band (XCD-local heuristic)
    const int nb = blockIdx.x >> 3;  // n-block within band (0..63)
    const int n0 = nb * BN;
    const int m0 = mb * BM;
    const int c0 = nb >> 3;          // own chunk / ring start (0..7)
    unsigned* bandflags = flags + mb * kNB;

    // ---- one-time: W-band -> register B-frags (f16), ring-permuted ----
    // Ring pos c -> physical chunk p(c) = (c0+c)&7; chunk = 8 windows of 32k,
    // wave q owns windows {q, 4+q}. wfrag[h][2c+j] = W[n0+h*16+l16] at
    // k = (p(c)*8 + j*4 + q)*32 + quad*8 .. +8.
    f16x8 wfrag[2][2 * NCH];
    #pragma unroll
    for (int h = 0; h < 2; ++h) {
        const float* wrow = W + (size_t)(n0 + h * 16 + l16) * kR;
        #pragma unroll
        for (int kki = 0; kki < 2 * NCH; ++kki) {
            const int kk = ((c0 + (kki >> 1)) & 7) * 8 + (kki & 1) * 4 + q;
            const float* p = wrow + kk * 32 + quad * 8;
            wfrag[h][kki] = cvt8(*(const float4*)p, *(const float4*)(p + 4));
        }
    }
    f16x8 winfrag[2] = {};
    if (q < 2) {
        #pragma unroll
        for (int h = 0; h < 2; ++h) {
            const float* p = Win + (size_t)(n0 + h * 16 + l16) * kIN + q * 32 + quad * 8;
            winfrag[h] = cvt8(*(const float4*)p, *(const float4*)(p + 4));
        }
    }

    // s staging geometry: rows tid>>4 (+16), cols (tid&15)*8 (+128) halfs.
    // 16 threads x 16 B = 256-B coalesced runs.
    const int srow = tid >> 4;             // 0..15
    const int sc8  = (tid & 15) * 8;       // halfs
    const size_t sgbase = (size_t)(m0 + srow) * kR + sc8;
    const int ldst = srow * SST + sc8;

    #pragma unroll 1
    for (int t = 0; t < kT; ++t) {
        // ---- X-frag raw loads for THIS step (latency hidden under sync) ----
        float4 xr[2][2];
        if (q < 2) {
            #pragma unroll
            for (int i = 0; i < 2; ++i) {
                const float* xp = X + ((size_t)(m0 + i * 16 + l16) * kT + t) * kIN
                                + q * 32 + quad * 8;
                xr[i][0] = *(const float4*)xp;
                xr[i][1] = *(const float4*)(xp + 4);
            }
        }

        f32x4 acc[2][2] = {};   // [m-tile][n-tile]

        // ---- recurrent term over s_{t-1}: 8 ring chunks, depth-2 prefetch ----
        if (t > 0) {
            const _Float16* sprev = (t & 1) ? sbuf0 : sbuf1;
            const unsigned target = (unsigned)t;   // flag >= t <=> s[t-1] published

            if (wave == 0) {
                u64 fm = poll_flags(bandflags, lane, target);
                while (!chunk_ready(fm, c0)) {
                    __builtin_amdgcn_s_sleep(1);
                    fm = poll_flags(bandflags, lane, target);
                }
                // ONE inv per block per step: drop stale s lines from L1/L2
                __builtin_amdgcn_fence(__ATOMIC_ACQUIRE, "agent");
                if (lane == 0) fm_sh = fm;
            }
            __syncthreads();
            u64 fmask = fm_sh;
            asm volatile("" ::: "memory");

            f16x8 rg[2][4];   // depth-2 register prefetch: [parity][granule]
            // ring-0 (own group, confirmed)
            #pragma unroll
            for (int g = 0; g < 4; ++g)
                rg[0][g] = *(const f16x8*)(sprev + sgbase + (size_t)(g >> 1) * 16 * kR
                                           + c0 * CH + (g & 1) * 128);
            // ring-1
            {
                const int pc1 = (c0 + 1) & 7;
                if (!chunk_ready(fmask, pc1)) {
                    do { __builtin_amdgcn_s_sleep(1);
                         fmask = poll_flags(bandflags, lane, target);
                    } while (!chunk_ready(fmask, pc1));
                }
                asm volatile("" ::: "memory");
                #pragma unroll
                for (int g = 0; g < 4; ++g)
                    rg[1][g] = *(const f16x8*)(sprev + sgbase + (size_t)(g >> 1) * 16 * kR
                                               + pc1 * CH + (g & 1) * 128);
            }
            // stage ring-0 into buf0
            #pragma unroll
            for (int g = 0; g < 4; ++g)
                *(f16x8*)&ss[0][ldst + (g >> 1) * 16 * SST + (g & 1) * 128] = rg[0][g];
            __syncthreads();

            #pragma unroll
            for (int c = 0; c < NCH; ++c) {
                const _Float16* buf = ss[c & 1];
                #pragma unroll
                for (int j = 0; j < 2; ++j) {
                    const int kloc = (j * 4 + q) * 32 + quad * 8;
                    f16x8 av0 = *(const f16x8*)&buf[(l16) * SST + kloc];
                    f16x8 av1 = *(const f16x8*)&buf[(16 + l16) * SST + kloc];
                    acc[0][0] = MFMA16(av0, wfrag[0][2 * c + j], acc[0][0]);
                    acc[0][1] = MFMA16(av0, wfrag[1][2 * c + j], acc[0][1]);
                    acc[1][0] = MFMA16(av1, wfrag[0][2 * c + j], acc[1][0]);
                    acc[1][1] = MFMA16(av1, wfrag[1][2 * c + j], acc[1][1]);
                }
                if (c + 2 < NCH) {   // issue loads 2 chunks ahead
                    const int pc = (c0 + c + 2) & 7;
                    if (!chunk_ready(fmask, pc)) {
                        do { __builtin_amdgcn_s_sleep(1);
                             fmask = poll_flags(bandflags, lane, target);
                        } while (!chunk_ready(fmask, pc));
                    }
                    asm volatile("" ::: "memory");
                    #pragma unroll
                    for (int g = 0; g < 4; ++g)
                        rg[c & 1][g] = *(const f16x8*)(sprev + sgbase
                                                       + (size_t)(g >> 1) * 16 * kR
                                                       + pc * CH + (g & 1) * 128);
                }
                if (c + 1 < NCH) {   // stage next chunk into the other buffer
                    #pragma unroll
                    for (int g = 0; g < 4; ++g)
                        *(f16x8*)&ss[(c + 1) & 1][ldst + (g >> 1) * 16 * SST + (g & 1) * 128]
                            = rg[(c + 1) & 1][g];
                }
                __syncthreads();
            }
        }

        // ---- input term (X loads long done) ----
        if (q < 2) {
            #pragma unroll
            for (int i = 0; i < 2; ++i) {
                f16x8 a = cvt8(xr[i][0], xr[i][1]);
                acc[i][0] = MFMA16(a, winfrag[0], acc[i][0]);
                acc[i][1] = MFMA16(a, winfrag[1], acc[i][1]);
            }
        }

        // ---- reduce 4 k-phase partials through LDS, tanh, store ----
        #pragma unroll
        for (int i = 0; i < 2; ++i)
            #pragma unroll
            for (int h = 0; h < 2; ++h)
                #pragma unroll
                for (int r = 0; r < 4; ++r)
                    pf[q * BM * PFS + (i * 16 + quad * 4 + r) * PFS + h * 16 + l16]
                        = acc[i][h][r];
        __syncthreads();

        // thread -> (m = tid>>3, 4 n at (tid&7)*4)
        const int ml = tid >> 3, nl4 = (tid & 7) * 4;
        f32x4 v0 = *(const f32x4*)&pf[0 * BM * PFS + ml * PFS + nl4];
        f32x4 v1 = *(const f32x4*)&pf[1 * BM * PFS + ml * PFS + nl4];
        f32x4 v2 = *(const f32x4*)&pf[2 * BM * PFS + ml * PFS + nl4];
        f32x4 v3 = *(const f32x4*)&pf[3 * BM * PFS + ml * PFS + nl4];
        float o0 = tanhf(v0[0] + v1[0] + v2[0] + v3[0]);
        float o1 = tanhf(v0[1] + v1[1] + v2[1] + v3[1]);
        float o2 = tanhf(v0[2] + v1[2] + v2[2] + v3[2]);
        float o3 = tanhf(v0[3] + v1[3] + v2[3] + v3[3]);

        if (t < kT - 1) {
            _Float16* sout = (t & 1) ? sbuf1 : sbuf0;
            union { u64 u; _Float16 h[4]; } pk;
            pk.h[0] = (_Float16)o0; pk.h[1] = (_Float16)o1;
            pk.h[2] = (_Float16)o2; pk.h[3] = (_Float16)o3;
            // single write-through store to the coherence point — no wbl2
            __hip_atomic_store((u64*)(sout + (size_t)(m0 + ml) * kR + n0 + nl4), pk.u,
                               __ATOMIC_RELAXED, __HIP_MEMORY_SCOPE_AGENT);
            __builtin_amdgcn_s_waitcnt(0);   // this thread's store completed
            __syncthreads();                 // whole block's stores completed; guards pf
            if (tid == 0)
                __hip_atomic_store(&bandflags[nb], (unsigned)(t + 1),
                                   __ATOMIC_RELAXED, __HIP_MEMORY_SCOPE_AGENT);
        } else {
            float4 o; o.x = o0; o.y = o1; o.z = o2; o.w = o3;
            *(float4*)(out + (size_t)(m0 + ml) * kR + n0 + nl4) = o;
        }
    }
}

extern "C" void kernel_launch(void* const* d_in, const int* in_sizes, int n_in,
                              void* d_out, int out_size, void* d_ws, size_t ws_size,
                              hipStream_t stream)
{
    const float* X   = (const float*)d_in[0];  // [B, T, IN]
    const float* Win = (const float*)d_in[1];  // [R, IN]
    const float* W   = (const float*)d_in[2];  // [R, R]
    float* out = (float*)d_out;                // [B, R]

    char* ws = (char*)d_ws;
    _Float16* s0 = (_Float16*)ws;                                  // 1 MB
    _Float16* s1 = (_Float16*)(ws + (size_t)kB * kR * 2);          // 1 MB
    unsigned* flags = (unsigned*)(ws + 2 * (size_t)kB * kR * 2);   // [8][64]

    hipMemsetAsync(flags, 0, kBands * kNB * sizeof(unsigned), stream);
    esn_persist<<<kBlocks, 256, 0, stream>>>(X, Win, W, out, s0, s1, flags);
}

// Round 11
// 3731.981 us; speedup vs baseline: 1.6729x; 1.6729x over previous
//
#include <hip/hip_runtime.h>
#include <hip/hip_fp16.h>
#include <cmath>

// Problem constants (reference: B=256, T=512, IN=64, R=2048)
constexpr int kB  = 256;
constexpr int kT  = 512;
constexpr int kIN = 64;
constexpr int kR  = 2048;

constexpr int kBands  = 8;             // m-bands; band = blockIdx&7 -> XCD-local under
                                       // round-robin dispatch (r9-verified: FETCH collapse)
constexpr int kNB     = 32;            // n-blocks per band
constexpr int kBlocks = kBands * kNB;  // 256 -> 1 block/CU (r10: 2/CU regresses)
constexpr int BM = 32;                 // batches per block
constexpr int BN = 64;                 // n per block (W-band in registers, nh-split)
constexpr int CH  = 512;               // k per staged s-chunk (= 8 producer blocks)
constexpr int NCH = kR / CH;           // 4 chunks
constexpr int SST = CH + 8;            // ss row stride (halfs) = 520
constexpr int PFS = 68;                // partial-scratch row stride (words)

typedef _Float16 f16x8 __attribute__((ext_vector_type(8)));
typedef float    f32x4 __attribute__((ext_vector_type(4)));
typedef unsigned long long u64;

#define MFMA16(a, b, c) __builtin_amdgcn_mfma_f32_16x16x32_f16((a), (b), (c), 0, 0, 0)

__device__ __forceinline__ f16x8 cvt8(float4 a, float4 b) {
    f16x8 v;
    v[0] = (_Float16)a.x; v[1] = (_Float16)a.y; v[2] = (_Float16)a.z; v[3] = (_Float16)a.w;
    v[4] = (_Float16)b.x; v[5] = (_Float16)b.y; v[6] = (_Float16)b.z; v[7] = (_Float16)b.w;
    return v;
}

// One coalesced poll of the band's 32 per-block flags (agent-scope, L3-fresh).
// Returns 32-bit mask: bit j set iff band-block j has published step >= target.
__device__ __forceinline__ unsigned poll32(const unsigned* f, int lane, unsigned target) {
    unsigned v = __hip_atomic_load(f + (lane & 31), __ATOMIC_RELAXED, __HIP_MEMORY_SCOPE_AGENT);
    return (unsigned)__ballot(v >= target);
}
// Chunk pc (512 k) is produced by band-blocks [8*pc, 8*pc+8).
__device__ __forceinline__ bool chunk_ready(unsigned fm, int pc) {
    return ((fm >> (8 * pc)) & 0xffu) == 0xffu;
}

// Persistent ESN, r11 = r9 (best: 3.42 ms) + critical-chain trims:
//   (1) steady-state full preload: if the post-inv mask shows the whole band
//       published (common case), issue chunks ring-0..2 immediately and ring-3
//       at c=0 — no in-loop polls, max MLP; else r9's depth-2 ring fallback;
//   (2) X loads for t+1 issued under the store drain (loop rotation);
//   (3) input-term MFMA moved before the flag wait (overlaps wave0 spin).
// Coherence (r5-proven, unchanged): agent-scope write-through s-stores ->
// s_waitcnt drain -> __syncthreads -> flag store; consumers: ONE acquire-inv
// per block per step, then plain cached coalesced loads.
__global__ __launch_bounds__(512, 2) void esn_persist(
    const float* __restrict__ X,     // [B, T, IN]
    const float* __restrict__ Win,   // [R, IN]
    const float* __restrict__ W,     // [R, R]
    float* __restrict__ out,         // [B, R]
    _Float16* __restrict__ sbuf0,
    _Float16* __restrict__ sbuf1,
    unsigned* __restrict__ flags)    // [8][32], zeroed at launch
{
    __shared__ __align__(16) _Float16 ss[2][BM * SST];   // 66560 B
    __shared__ __align__(16) float pf[4 * BM * PFS];     // 34816 B
    __shared__ unsigned fm_sh;

    const int tid  = threadIdx.x;
    const int wave = tid >> 6, lane = tid & 63;
    const int quad = lane >> 4, l16 = lane & 15;
    const int nh = wave >> 2;        // n-half: cols [nh*32, nh*32+32)
    const int q  = wave & 3;         // k-phase: window ≡ q (mod 4)
    const int mb = blockIdx.x & 7;   // band (XCD-local heuristic)
    const int nb = blockIdx.x >> 3;  // n-block within band
    const int n0 = nb * BN;
    const int m0 = mb * BM;
    const int c0 = nb >> 3;          // own chunk / ring start (0..3)
    unsigned* bandflags = flags + mb * kNB;

    // ---- one-time: W-band -> register B-frags (f16), ring-permuted ----
    // Ring pos c -> physical chunk p(c) = (c0+c)&3.
    // wfrag[h][4c+j] = W[n0+nh*32+h*16+l16][kk*32+quad*8+..], kk = p(c)*16+4j+q
    f16x8 wfrag[2][4 * NCH];
    #pragma unroll
    for (int h = 0; h < 2; ++h) {
        const float* wrow = W + (size_t)(n0 + nh * 32 + h * 16 + l16) * kR;
        #pragma unroll
        for (int kki = 0; kki < 4 * NCH; ++kki) {
            const int kk = (((c0 + (kki >> 2)) & 3) << 4) + (kki & 3) * 4 + q;
            const float* p = wrow + kk * 32 + quad * 8;
            wfrag[h][kki] = cvt8(*(const float4*)p, *(const float4*)(p + 4));
        }
    }
    f16x8 winfrag[2] = {};
    if (q < 2) {
        #pragma unroll
        for (int h = 0; h < 2; ++h) {
            const float* p = Win + (size_t)(n0 + nh * 32 + h * 16 + l16) * kIN
                           + q * 32 + quad * 8;
            winfrag[h] = cvt8(*(const float4*)p, *(const float4*)(p + 4));
        }
    }

    // s staging geometry: thread -> row tid>>4 (0..31), 4 x 16B units at
    // (tid&15 + g*16)*16B within the 1024-B chunk row. Coalesced 256-B runs.
    const int srow = tid >> 4;
    const int su8  = (tid & 15) * 8;                 // halfs
    const size_t sgbase = (size_t)(m0 + srow) * kR + su8;
    const int ldst = srow * SST + su8;               // LDS halfs offset

    // X-frags for step 0 (rotated: subsequent steps load under the drain)
    float4 xr[2][2];
    if (q < 2) {
        #pragma unroll
        for (int i = 0; i < 2; ++i) {
            const float* xp = X + ((size_t)(m0 + i * 16 + l16) * kT + 0) * kIN
                            + q * 32 + quad * 8;
            xr[i][0] = *(const float4*)xp;
            xr[i][1] = *(const float4*)(xp + 4);
        }
    }

    #pragma unroll 1
    for (int t = 0; t < kT; ++t) {
        f32x4 acc[2][2] = {};   // [m-tile][n-tile within n-half]

        // ---- input term first: overlaps wave0's flag spin below ----
        if (q < 2) {
            #pragma unroll
            for (int i = 0; i < 2; ++i) {
                f16x8 a = cvt8(xr[i][0], xr[i][1]);
                acc[i][0] = MFMA16(a, winfrag[0], acc[i][0]);
                acc[i][1] = MFMA16(a, winfrag[1], acc[i][1]);
            }
        }

        // ---- recurrent term over s_{t-1}: 4 chunks ----
        if (t > 0) {
            const _Float16* sprev = (t & 1) ? sbuf0 : sbuf1;
            const unsigned target = (unsigned)t;   // flag >= t <=> s[t-1] published

            if (wave == 0) {
                unsigned fm = poll32(bandflags, lane, target);
                while (!chunk_ready(fm, c0)) {
                    __builtin_amdgcn_s_sleep(1);
                    fm = poll32(bandflags, lane, target);
                }
                // ONE inv per block per step: drop stale s lines from L1/L2
                __builtin_amdgcn_fence(__ATOMIC_ACQUIRE, "agent");
                if (lane == 0) fm_sh = fm;
            }
            __syncthreads();
            unsigned fmask = fm_sh;
            asm volatile("" ::: "memory");

            const bool allready = (fmask == 0xffffffffu);  // wave-uniform
            f16x8 rg[NCH][4];   // register prefetch, ring-indexed

            if (allready) {
                // whole band published: issue ring-0..2 back-to-back (max MLP)
                #pragma unroll
                for (int c = 0; c < 3; ++c) {
                    const size_t off = (size_t)((c0 + c) & 3) * CH;
                    #pragma unroll
                    for (int g = 0; g < 4; ++g)
                        rg[c][g] = *(const f16x8*)(sprev + sgbase + off + g * 128);
                }
            } else {
                // r9 fallback: ring-0 (own, confirmed), then wait + ring-1
                #pragma unroll
                for (int g = 0; g < 4; ++g)
                    rg[0][g] = *(const f16x8*)(sprev + sgbase + (size_t)c0 * CH + g * 128);
                const int pc1 = (c0 + 1) & 3;
                if (!chunk_ready(fmask, pc1)) {
                    do { __builtin_amdgcn_s_sleep(1);
                         fmask = poll32(bandflags, lane, target);
                    } while (!chunk_ready(fmask, pc1));
                }
                asm volatile("" ::: "memory");
                #pragma unroll
                for (int g = 0; g < 4; ++g)
                    rg[1][g] = *(const f16x8*)(sprev + sgbase + (size_t)pc1 * CH + g * 128);
            }
            // stage ring-0 into buf0
            #pragma unroll
            for (int g = 0; g < 4; ++g)
                *(f16x8*)&ss[0][ldst + g * 128] = rg[0][g];
            __syncthreads();

            #pragma unroll
            for (int c = 0; c < NCH; ++c) {
                const _Float16* buf = ss[c & 1];
                #pragma unroll
                for (int j = 0; j < 4; ++j) {
                    const int kloc = (4 * j + q) * 32 + quad * 8;
                    f16x8 av0 = *(const f16x8*)&buf[(l16) * SST + kloc];
                    f16x8 av1 = *(const f16x8*)&buf[(16 + l16) * SST + kloc];
                    acc[0][0] = MFMA16(av0, wfrag[0][4 * c + j], acc[0][0]);
                    acc[0][1] = MFMA16(av0, wfrag[1][4 * c + j], acc[0][1]);
                    acc[1][0] = MFMA16(av1, wfrag[0][4 * c + j], acc[1][0]);
                    acc[1][1] = MFMA16(av1, wfrag[1][4 * c + j], acc[1][1]);
                }
                if (c + 2 < NCH) {
                    if (allready) {
                        if (c == 0) {   // ring-3 issued here (0..2 preloaded)
                            const size_t off = (size_t)((c0 + 3) & 3) * CH;
                            #pragma unroll
                            for (int g = 0; g < 4; ++g)
                                rg[3][g] = *(const f16x8*)(sprev + sgbase + off + g * 128);
                        }
                    } else {
                        const int pc = (c0 + c + 2) & 3;
                        if (!chunk_ready(fmask, pc)) {
                            do { fmask = poll32(bandflags, lane, target);
                            } while (!chunk_ready(fmask, pc));
                        }
                        asm volatile("" ::: "memory");
                        const size_t off = (size_t)pc * CH;
                        #pragma unroll
                        for (int g = 0; g < 4; ++g)
                            rg[c + 2][g] = *(const f16x8*)(sprev + sgbase + off + g * 128);
                    }
                }
                if (c + 1 < NCH) {   // stage next chunk into the other buffer
                    #pragma unroll
                    for (int g = 0; g < 4; ++g)
                        *(f16x8*)&ss[(c + 1) & 1][ldst + g * 128] = rg[c + 1][g];
                }
                __syncthreads();
            }
        }

        // ---- reduce 4 k-phase partials through LDS, tanh, store ----
        #pragma unroll
        for (int i = 0; i < 2; ++i)
            #pragma unroll
            for (int h = 0; h < 2; ++h)
                #pragma unroll
                for (int r = 0; r < 4; ++r)
                    pf[q * BM * PFS + (i * 16 + quad * 4 + r) * PFS + nh * 32 + h * 16 + l16]
                        = acc[i][h][r];
        __syncthreads();

        // thread -> (m = tid>>4, 4 n at (tid&15)*4)
        const int ml = tid >> 4, nl4 = (tid & 15) * 4;
        f32x4 v0 = *(const f32x4*)&pf[0 * BM * PFS + ml * PFS + nl4];
        f32x4 v1 = *(const f32x4*)&pf[1 * BM * PFS + ml * PFS + nl4];
        f32x4 v2 = *(const f32x4*)&pf[2 * BM * PFS + ml * PFS + nl4];
        f32x4 v3 = *(const f32x4*)&pf[3 * BM * PFS + ml * PFS + nl4];
        float o0 = tanhf(v0[0] + v1[0] + v2[0] + v3[0]);
        float o1 = tanhf(v0[1] + v1[1] + v2[1] + v3[1]);
        float o2 = tanhf(v0[2] + v1[2] + v2[2] + v3[2]);
        float o3 = tanhf(v0[3] + v1[3] + v2[3] + v3[3]);

        if (t < kT - 1) {
            _Float16* sout = (t & 1) ? sbuf1 : sbuf0;
            union { u64 u; _Float16 h[4]; } pk;
            pk.h[0] = (_Float16)o0; pk.h[1] = (_Float16)o1;
            pk.h[2] = (_Float16)o2; pk.h[3] = (_Float16)o3;
            // single write-through store to the coherence point
            __hip_atomic_store((u64*)(sout + (size_t)(m0 + ml) * kR + n0 + nl4), pk.u,
                               __ATOMIC_RELAXED, __HIP_MEMORY_SCOPE_AGENT);
            // rotated X loads for t+1: their latency rides the store drain
            if (q < 2) {
                #pragma unroll
                for (int i = 0; i < 2; ++i) {
                    const float* xp = X + ((size_t)(m0 + i * 16 + l16) * kT + (t + 1)) * kIN
                                    + q * 32 + quad * 8;
                    xr[i][0] = *(const float4*)xp;
                    xr[i][1] = *(const float4*)(xp + 4);
                }
            }
            __builtin_amdgcn_s_waitcnt(0);   // s-store (and X loads) completed
            __syncthreads();                 // whole block's stores completed; guards pf
            if (tid == 0)
                __hip_atomic_store(&bandflags[nb], (unsigned)(t + 1),
                                   __ATOMIC_RELAXED, __HIP_MEMORY_SCOPE_AGENT);
        } else {
            float4 o; o.x = o0; o.y = o1; o.z = o2; o.w = o3;
            *(float4*)(out + (size_t)(m0 + ml) * kR + n0 + nl4) = o;
        }
    }
}

extern "C" void kernel_launch(void* const* d_in, const int* in_sizes, int n_in,
                              void* d_out, int out_size, void* d_ws, size_t ws_size,
                              hipStream_t stream)
{
    const float* X   = (const float*)d_in[0];  // [B, T, IN]
    const float* Win = (const float*)d_in[1];  // [R, IN]
    const float* W   = (const float*)d_in[2];  // [R, R]
    float* out = (float*)d_out;                // [B, R]

    char* ws = (char*)d_ws;
    _Float16* s0 = (_Float16*)ws;                                  // 1 MB
    _Float16* s1 = (_Float16*)(ws + (size_t)kB * kR * 2);          // 1 MB
    unsigned* flags = (unsigned*)(ws + 2 * (size_t)kB * kR * 2);   // [8][32]

    hipMemsetAsync(flags, 0, kBands * kNB * sizeof(unsigned), stream);
    esn_persist<<<kBlocks, 512, 0, stream>>>(X, Win, W, out, s0, s1, flags);
}

// Round 12
// 2433.072 us; speedup vs baseline: 2.5660x; 1.5339x over previous
//
#include <hip/hip_runtime.h>
#include <hip/hip_fp16.h>
#include <cmath>

// Problem constants (reference: B=256, T=512, IN=64, R=2048)
constexpr int kB  = 256;
constexpr int kT  = 512;
constexpr int kIN = 64;
constexpr int kR  = 2048;

constexpr int kBands  = 8;             // m-bands; band = blockIdx&7 -> XCD-local under
                                       // round-robin dispatch (r9-verified: FETCH collapse)
constexpr int kNB     = 32;            // n-blocks per band
constexpr int kBlocks = kBands * kNB;  // 256 -> 1 block/CU (r10: 2/CU regresses)
constexpr int BM = 32;                 // batches per block
constexpr int BN = 64;                 // n per block (W-band in registers, nh-split)
constexpr int CH  = 512;               // k per staged s-chunk (= 8 producer blocks)
constexpr int NCH = kR / CH;           // 4 chunks
constexpr int SST = CH + 8;            // ss row stride (halfs) = 520
constexpr int PFS = 68;                // partial-scratch row stride (words)

typedef _Float16 f16x8 __attribute__((ext_vector_type(8)));
typedef float    f32x4 __attribute__((ext_vector_type(4)));
typedef unsigned long long u64;

#define MFMA16(a, b, c) __builtin_amdgcn_mfma_f32_16x16x32_f16((a), (b), (c), 0, 0, 0)

__device__ __forceinline__ f16x8 cvt8(float4 a, float4 b) {
    f16x8 v;
    v[0] = (_Float16)a.x; v[1] = (_Float16)a.y; v[2] = (_Float16)a.z; v[3] = (_Float16)a.w;
    v[4] = (_Float16)b.x; v[5] = (_Float16)b.y; v[6] = (_Float16)b.z; v[7] = (_Float16)b.w;
    return v;
}

__device__ __forceinline__ unsigned get_xcc_id() {
    unsigned x;
    asm volatile("s_getreg_b32 %0, hwreg(HW_REG_XCC_ID, 0, 8)" : "=s"(x));
    return x & 0xfu;
}

// One coalesced poll of the band's 32 per-block flags (agent-scope, L3-fresh).
// Returns 32-bit mask: bit j set iff band-block j has published step >= target.
__device__ __forceinline__ unsigned poll32(const unsigned* f, int lane, unsigned target) {
    unsigned v = __hip_atomic_load(f + (lane & 31), __ATOMIC_RELAXED, __HIP_MEMORY_SCOPE_AGENT);
    return (unsigned)__ballot(v >= target);
}
// Chunk pc (512 k) is produced by band-blocks [8*pc, 8*pc+8).
__device__ __forceinline__ bool chunk_ready(unsigned fm, int pc) {
    return ((fm >> (8 * pc)) & 0xffu) == 0xffu;
}

// Persistent ESN, r12 = r9 (best verified: 3.42 ms) + XCD-verified fast
// coherence path. Theory: the per-step agent buffer_inv (L2 invalidate) in
// all 32 blocks of an XCD serializes at the shared L2 (~0.2-0.3 us each,
// r4->r5 evidence) and IS the 6-7 us/step plateau.
//   - Each block publishes its HW XCC_ID; at t==1 each block verifies its
//     whole band shares its XCD (bands are closed producer/consumer systems).
//   - Fast path (verified co-located, t>=2): plain write-back s-stores (the
//     band's s lives in the ONE shared per-XCD L2; peers' stores update it
//     directly) + L1-only `buffer_inv sc0` (per-CU, parallel).
//   - Safe path (any producer remote): r9 protocol byte-for-byte (agent
//     write-through stores + agent acquire-inv). Correctness never depends
//     on dispatch placement.
__global__ __launch_bounds__(512, 2) void esn_persist(
    const float* __restrict__ X,     // [B, T, IN]
    const float* __restrict__ Win,   // [R, IN]
    const float* __restrict__ W,     // [R, R]
    float* __restrict__ out,         // [B, R]
    _Float16* __restrict__ sbuf0,
    _Float16* __restrict__ sbuf1,
    unsigned* __restrict__ flags,    // [8][32], zeroed at launch
    unsigned* __restrict__ xcds)     // [8][32], zeroed at launch
{
    __shared__ __align__(16) _Float16 ss[2][BM * SST];   // 66560 B
    __shared__ __align__(16) float pf[4 * BM * PFS];     // 34816 B
    __shared__ unsigned fm_sh;
    __shared__ int fast_sh;

    const int tid  = threadIdx.x;
    const int wave = tid >> 6, lane = tid & 63;
    const int quad = lane >> 4, l16 = lane & 15;
    const int nh = wave >> 2;        // n-half: cols [nh*32, nh*32+32)
    const int q  = wave & 3;         // k-phase: window ≡ q (mod 4)
    const int mb = blockIdx.x & 7;   // band (XCD-local heuristic, HW-verified below)
    const int nb = blockIdx.x >> 3;  // n-block within band
    const int n0 = nb * BN;
    const int m0 = mb * BM;
    const int c0 = nb >> 3;          // own chunk / ring start (0..3)
    unsigned* bandflags = flags + mb * kNB;
    unsigned* bandxcc   = xcds  + mb * kNB;

    if (tid == 0) {
        fast_sh = 0;
        // publish this block's XCD id (+1 so 0 = unpublished); drained by the
        // t==0 epilogue's s_waitcnt before flag=1, so flag>=1 implies visible.
        __hip_atomic_store(&bandxcc[nb], get_xcc_id() + 1u,
                           __ATOMIC_RELAXED, __HIP_MEMORY_SCOPE_AGENT);
    }

    // ---- one-time: W-band -> register B-frags (f16), ring-permuted ----
    // Ring pos c -> physical chunk p(c) = (c0+c)&3.
    // wfrag[h][4c+j] = W[n0+nh*32+h*16+l16][kk*32+quad*8+..], kk = p(c)*16+4j+q
    f16x8 wfrag[2][4 * NCH];
    #pragma unroll
    for (int h = 0; h < 2; ++h) {
        const float* wrow = W + (size_t)(n0 + nh * 32 + h * 16 + l16) * kR;
        #pragma unroll
        for (int kki = 0; kki < 4 * NCH; ++kki) {
            const int kk = (((c0 + (kki >> 2)) & 3) << 4) + (kki & 3) * 4 + q;
            const float* p = wrow + kk * 32 + quad * 8;
            wfrag[h][kki] = cvt8(*(const float4*)p, *(const float4*)(p + 4));
        }
    }
    f16x8 winfrag[2] = {};
    if (q < 2) {
        #pragma unroll
        for (int h = 0; h < 2; ++h) {
            const float* p = Win + (size_t)(n0 + nh * 32 + h * 16 + l16) * kIN
                           + q * 32 + quad * 8;
            winfrag[h] = cvt8(*(const float4*)p, *(const float4*)(p + 4));
        }
    }

    // s staging geometry: thread -> row tid>>4 (0..31), 4 x 16B units at
    // (tid&15)*16B (+256B) within the 1024-B chunk row. Coalesced 256-B runs.
    const int srow = tid >> 4;
    const int su8  = (tid & 15) * 8;                 // halfs
    const size_t sgbase = (size_t)(m0 + srow) * kR + su8;
    const int ldst = srow * SST + su8;               // LDS halfs offset

    unsigned fastw = 0;   // wave0's register copy of the fast-path predicate

    #pragma unroll 1
    for (int t = 0; t < kT; ++t) {
        // ---- X-frag raw loads for THIS step (latency hidden under sync) ----
        float4 xr[2][2];
        if (q < 2) {
            #pragma unroll
            for (int i = 0; i < 2; ++i) {
                const float* xp = X + ((size_t)(m0 + i * 16 + l16) * kT + t) * kIN
                                + q * 32 + quad * 8;
                xr[i][0] = *(const float4*)xp;
                xr[i][1] = *(const float4*)(xp + 4);
            }
        }

        f32x4 acc[2][2] = {};   // [m-tile][n-tile within n-half]

        // ---- recurrent term over s_{t-1}: 4 chunks, depth-2 prefetch ----
        if (t > 0) {
            const _Float16* sprev = (t & 1) ? sbuf0 : sbuf1;
            const unsigned target = (unsigned)t;   // flag >= t <=> s[t-1] published

            if (wave == 0) {
                unsigned fm = poll32(bandflags, lane, target);
                if (t == 1) {
                    // one-time: wait for the WHOLE band, then verify XCD
                    // co-location (xcds visible once flags >= 1).
                    while (fm != 0xffffffffu) {
                        __builtin_amdgcn_s_sleep(1);
                        fm = poll32(bandflags, lane, target);
                    }
                    const unsigned myx = get_xcc_id() + 1u;
                    unsigned px = __hip_atomic_load(bandxcc + (lane & 31),
                                                    __ATOMIC_RELAXED,
                                                    __HIP_MEMORY_SCOPE_AGENT);
                    const bool same = (__ballot(px == myx) == ~0ull);
                    fastw = same ? 1u : 0u;
                    if (lane == 0) fast_sh = (int)fastw;
                } else {
                    while (!chunk_ready(fm, c0)) {
                        __builtin_amdgcn_s_sleep(1);
                        fm = poll32(bandflags, lane, target);
                    }
                }
                if (fastw && t >= 2) {
                    // fast: L1-only invalidate (per-CU, parallel). s lives in
                    // this XCD's shared L2, updated directly by peers' stores.
                    asm volatile("buffer_inv sc0" ::: "memory");
                } else {
                    // safe: full agent acquire (L1+L2 invalidate)
                    __builtin_amdgcn_fence(__ATOMIC_ACQUIRE, "agent");
                }
                if (lane == 0) fm_sh = fm;
            }
            __syncthreads();
            unsigned fmask = fm_sh;
            asm volatile("" ::: "memory");

            f16x8 rg[2][4];      // depth-2 register prefetch
            // chunk ring-0 (own, confirmed) loads
            #pragma unroll
            for (int g = 0; g < 4; ++g)
                rg[0][g] = *(const f16x8*)(sprev + sgbase + c0 * CH + g * 128);
            // chunk ring-1
            {
                const int pc1 = (c0 + 1) & 3;
                if (!chunk_ready(fmask, pc1)) {
                    do { __builtin_amdgcn_s_sleep(1);
                         fmask = poll32(bandflags, lane, target);
                    } while (!chunk_ready(fmask, pc1));
                }
                asm volatile("" ::: "memory");
                #pragma unroll
                for (int g = 0; g < 4; ++g)
                    rg[1][g] = *(const f16x8*)(sprev + sgbase + pc1 * CH + g * 128);
            }
            // stage ring-0 into buf0
            #pragma unroll
            for (int g = 0; g < 4; ++g)
                *(f16x8*)&ss[0][ldst + g * 128] = rg[0][g];
            __syncthreads();

            #pragma unroll
            for (int c = 0; c < NCH; ++c) {
                const _Float16* buf = ss[c & 1];
                #pragma unroll
                for (int j = 0; j < 4; ++j) {
                    const int kloc = (4 * j + q) * 32 + quad * 8;
                    f16x8 av0 = *(const f16x8*)&buf[(l16) * SST + kloc];
                    f16x8 av1 = *(const f16x8*)&buf[(16 + l16) * SST + kloc];
                    acc[0][0] = MFMA16(av0, wfrag[0][4 * c + j], acc[0][0]);
                    acc[0][1] = MFMA16(av0, wfrag[1][4 * c + j], acc[0][1]);
                    acc[1][0] = MFMA16(av1, wfrag[0][4 * c + j], acc[1][0]);
                    acc[1][1] = MFMA16(av1, wfrag[1][4 * c + j], acc[1][1]);
                }
                if (c + 2 < NCH) {   // issue loads 2 chunks ahead
                    const int pc = (c0 + c + 2) & 3;
                    if (!chunk_ready(fmask, pc)) {
                        do { __builtin_amdgcn_s_sleep(1);
                             fmask = poll32(bandflags, lane, target);
                        } while (!chunk_ready(fmask, pc));
                    }
                    asm volatile("" ::: "memory");
                    #pragma unroll
                    for (int g = 0; g < 4; ++g)
                        rg[c & 1][g] = *(const f16x8*)(sprev + sgbase + pc * CH + g * 128);
                }
                if (c + 1 < NCH) {   // stage next chunk into the other buffer
                    #pragma unroll
                    for (int g = 0; g < 4; ++g)
                        *(f16x8*)&ss[(c + 1) & 1][ldst + g * 128] = rg[(c + 1) & 1][g];
                }
                __syncthreads();
            }
        }

        // ---- input term (X loads long done) ----
        if (q < 2) {
            #pragma unroll
            for (int i = 0; i < 2; ++i) {
                f16x8 a = cvt8(xr[i][0], xr[i][1]);
                acc[i][0] = MFMA16(a, winfrag[0], acc[i][0]);
                acc[i][1] = MFMA16(a, winfrag[1], acc[i][1]);
            }
        }

        // ---- reduce 4 k-phase partials through LDS, tanh, store ----
        #pragma unroll
        for (int i = 0; i < 2; ++i)
            #pragma unroll
            for (int h = 0; h < 2; ++h)
                #pragma unroll
                for (int r = 0; r < 4; ++r)
                    pf[q * BM * PFS + (i * 16 + quad * 4 + r) * PFS + nh * 32 + h * 16 + l16]
                        = acc[i][h][r];
        __syncthreads();

        // thread -> (m = tid>>4, 4 n at (tid&15)*4)
        const int ml = tid >> 4, nl4 = (tid & 15) * 4;
        f32x4 v0 = *(const f32x4*)&pf[0 * BM * PFS + ml * PFS + nl4];
        f32x4 v1 = *(const f32x4*)&pf[1 * BM * PFS + ml * PFS + nl4];
        f32x4 v2 = *(const f32x4*)&pf[2 * BM * PFS + ml * PFS + nl4];
        f32x4 v3 = *(const f32x4*)&pf[3 * BM * PFS + ml * PFS + nl4];
        float o0 = tanhf(v0[0] + v1[0] + v2[0] + v3[0]);
        float o1 = tanhf(v0[1] + v1[1] + v2[1] + v3[1]);
        float o2 = tanhf(v0[2] + v1[2] + v2[2] + v3[2]);
        float o3 = tanhf(v0[3] + v1[3] + v2[3] + v3[3]);

        if (t < kT - 1) {
            _Float16* sout = (t & 1) ? sbuf1 : sbuf0;
            union { u64 u; _Float16 h[4]; } pk;
            pk.h[0] = (_Float16)o0; pk.h[1] = (_Float16)o1;
            pk.h[2] = (_Float16)o2; pk.h[3] = (_Float16)o3;
            u64* dst = (u64*)(sout + (size_t)(m0 + ml) * kR + n0 + nl4);
            // fast_sh valid from t>=1 (set during t==1 detect, before the
            // chunk-loop barriers); t==0 epilogue reads the init value 0.
            if (fast_sh) {
                *dst = pk.u;                     // write-back: lands in the
                asm volatile("" ::: "memory");   // XCD's shared L2 (verified)
            } else {
                __hip_atomic_store(dst, pk.u, __ATOMIC_RELAXED,
                                   __HIP_MEMORY_SCOPE_AGENT);  // through to L3
            }
            __builtin_amdgcn_s_waitcnt(0);   // store (and xcc publish) completed
            __syncthreads();                 // whole block's stores completed; guards pf
            if (tid == 0)
                __hip_atomic_store(&bandflags[nb], (unsigned)(t + 1),
                                   __ATOMIC_RELAXED, __HIP_MEMORY_SCOPE_AGENT);
        } else {
            float4 o; o.x = o0; o.y = o1; o.z = o2; o.w = o3;
            *(float4*)(out + (size_t)(m0 + ml) * kR + n0 + nl4) = o;
        }
    }
}

extern "C" void kernel_launch(void* const* d_in, const int* in_sizes, int n_in,
                              void* d_out, int out_size, void* d_ws, size_t ws_size,
                              hipStream_t stream)
{
    const float* X   = (const float*)d_in[0];  // [B, T, IN]
    const float* Win = (const float*)d_in[1];  // [R, IN]
    const float* W   = (const float*)d_in[2];  // [R, R]
    float* out = (float*)d_out;                // [B, R]

    char* ws = (char*)d_ws;
    _Float16* s0 = (_Float16*)ws;                                  // 1 MB
    _Float16* s1 = (_Float16*)(ws + (size_t)kB * kR * 2);          // 1 MB
    unsigned* flags = (unsigned*)(ws + 2 * (size_t)kB * kR * 2);   // [8][32]
    unsigned* xcds  = flags + kBands * kNB;                        // [8][32]

    hipMemsetAsync(flags, 0, 2 * kBands * kNB * sizeof(unsigned), stream);
    esn_persist<<<kBlocks, 512, 0, stream>>>(X, Win, W, out, s0, s1, flags, xcds);
}